// Round 1
// baseline (123.662 us; speedup 1.0000x reference)
//
#include <hip/hip_runtime.h>
#include <hip/hip_bf16.h>

// Problem constants (reference: Ex/Ey [8192,256] f32, out [8192] f32)
#define NROWS 8192
#define DDIM  256
#define TILE  128
#define BK    64

typedef __bf16 bf16x8 __attribute__((ext_vector_type(8)));
typedef float  f32x4  __attribute__((ext_vector_type(4)));

// exp(LOG_NORM - 0.5*z^2), z=(c-1)/0.05  ==  exp2(LOG2K - 288.539008*(c-1)^2)
// LOG_NORM = -0.5*ln(2pi) - ln(0.05) = 2.0767937403 ; /ln2 = 2.996180025
#define LOG2K      2.99618003f
#define NEG_COEF  -288.53900818f   // -0.5 * 400 / ln(2)

__global__ void zero_kernel(float* __restrict__ out) {
    out[blockIdx.x * 256 + threadIdx.x] = 0.0f;
}

// One block per row: compute 1/max(||row||,eps), emit normalized bf16 row.
__global__ void normalize_kernel(const float* __restrict__ E,
                                 __hip_bfloat16* __restrict__ O) {
    const int row = blockIdx.x;
    const int t   = threadIdx.x;          // 256 threads == D
    float v  = E[(size_t)row * DDIM + t];
    float ss = v * v;
#pragma unroll
    for (int o = 32; o > 0; o >>= 1) ss += __shfl_down(ss, o);
    __shared__ float wsum[4];
    if ((t & 63) == 0) wsum[t >> 6] = ss;
    __syncthreads();
    const float tot = wsum[0] + wsum[1] + wsum[2] + wsum[3];
    const float inv = 1.0f / fmaxf(sqrtf(tot), 1e-8f);
    O[(size_t)row * DDIM + t] = __float2bfloat16(v * inv);
}

__device__ inline void async_load16(const void* g, void* l) {
    __builtin_amdgcn_global_load_lds(
        (const __attribute__((address_space(1))) unsigned int*)g,
        (__attribute__((address_space(3))) unsigned int*)l, 16, 0, 0);
}

// C = Xn * Yn^T fused with gaussian + column-sum.
// 128x128 tile, 4 waves in 2x2, BK=64, mfma 16x16x32 bf16.
__global__ __launch_bounds__(256) void cosgauss_gemm(
    const __hip_bfloat16* __restrict__ Xn,
    const __hip_bfloat16* __restrict__ Yn,
    float* __restrict__ out) {
    __shared__ __hip_bfloat16 As[TILE * BK];   // [row][k], row-major, 16 KB
    __shared__ __hip_bfloat16 Bs[TILE * BK];   // [col][k], row-major, 16 KB
    __shared__ float colpart[TILE];

    const int tid  = threadIdx.x;
    const int lane = tid & 63;
    const int w    = tid >> 6;       // wave 0..3
    const int wr   = w >> 1;         // wave row 0..1 (64 rows each)
    const int wc   = w & 1;          // wave col 0..1 (64 cols each)
    const int rowBase = blockIdx.y * TILE;
    const int colBase = blockIdx.x * TILE;

    const __hip_bfloat16* Ag = Xn + (size_t)rowBase * DDIM;
    const __hip_bfloat16* Bg = Yn + (size_t)colBase * DDIM;

    f32x4 acc[4][4] = {};

    const int lr = lane >> 3;        // staging: sub-row within 8-row chunk
    const int cb = (lane & 7) * 8;   // staging: k-element offset (16 B)
    const int lm = lane & 15;        // mfma: m (A) / n (B) index
    const int kq = lane >> 4;        // mfma: k-quad

    for (int kt = 0; kt < DDIM; kt += BK) {
        __syncthreads();             // LDS reuse guard
#pragma unroll
        for (int j = 0; j < 4; ++j) {
            const int chunk = w * 4 + j;            // 0..15 (8 rows each)
            const int r = chunk * 8 + lr;
            async_load16(Ag + (size_t)r * DDIM + kt + cb, (char*)As + chunk * 1024);
            async_load16(Bg + (size_t)r * DDIM + kt + cb, (char*)Bs + chunk * 1024);
        }
        __syncthreads();             // waits vmcnt(0) for global_load_lds

        const __bf16* Ap = (const __bf16*)As;
        const __bf16* Bp = (const __bf16*)Bs;
#pragma unroll
        for (int kk = 0; kk < BK; kk += 32) {
            bf16x8 a[4], b[4];
#pragma unroll
            for (int rf = 0; rf < 4; ++rf)
                a[rf] = *(const bf16x8*)(Ap + (wr * 64 + rf * 16 + lm) * BK + kk + kq * 8);
#pragma unroll
            for (int cf = 0; cf < 4; ++cf)
                b[cf] = *(const bf16x8*)(Bp + (wc * 64 + cf * 16 + lm) * BK + kk + kq * 8);
#pragma unroll
            for (int rf = 0; rf < 4; ++rf)
#pragma unroll
                for (int cf = 0; cf < 4; ++cf)
                    acc[rf][cf] = __builtin_amdgcn_mfma_f32_16x16x32_bf16(
                        a[rf], b[cf], acc[rf][cf], 0, 0, 0);
        }
    }

    // Epilogue: gaussian + column sums.
    // C/D layout: col = lane&15, row = (lane>>4)*4 + reg  [m89/m91 verified]
    float s[4];
#pragma unroll
    for (int cf = 0; cf < 4; ++cf) {
        float t = 0.0f;
#pragma unroll
        for (int rf = 0; rf < 4; ++rf) {
#pragma unroll
            for (int i = 0; i < 4; ++i) {
                const float d = acc[rf][cf][i] - 1.0f;
                t += exp2f(fmaf(d * d, NEG_COEF, LOG2K));
            }
        }
        // reduce over the 4 quads (rows) -> all lanes hold 64-row column sum
        t += __shfl_xor(t, 16);
        t += __shfl_xor(t, 32);
        s[cf] = t;
    }
    // lane l holds column (wc*64 + l): cf = l>>4, within-frag col = l&15
    const float v = (lane < 16) ? s[0] : (lane < 32) ? s[1] : (lane < 48) ? s[2] : s[3];
    const int c = wc * 64 + lane;    // 0..127 within tile
    if (wr == 0) colpart[c] = v;
    __syncthreads();
    if (wr == 1) atomicAdd(&out[colBase + c], v + colpart[c]);
}

extern "C" void kernel_launch(void* const* d_in, const int* in_sizes, int n_in,
                              void* d_out, int out_size, void* d_ws, size_t ws_size,
                              hipStream_t stream) {
    const float* Ex = (const float*)d_in[0];
    const float* Ey = (const float*)d_in[1];
    float* out = (float*)d_out;

    __hip_bfloat16* Xn = (__hip_bfloat16*)d_ws;                    // 4 MB
    __hip_bfloat16* Yn = Xn + (size_t)NROWS * DDIM;                // +4 MB

    zero_kernel<<<NROWS / 256, 256, 0, stream>>>(out);             // out_size==8192
    normalize_kernel<<<NROWS, 256, 0, stream>>>(Ex, Xn);
    normalize_kernel<<<NROWS, 256, 0, stream>>>(Ey, Yn);

    dim3 grid(NROWS / TILE, NROWS / TILE);                         // 64 x 64 tiles
    cosgauss_gemm<<<grid, 256, 0, stream>>>(Xn, Yn, out);
}

// Round 2
// 107.189 us; speedup vs baseline: 1.1537x; 1.1537x over previous
//
#include <hip/hip_runtime.h>
#include <hip/hip_bf16.h>

// Problem constants (reference: Ex/Ey [8192,256] f32, out [8192] f32)
#define NROWS 8192
#define DDIM  256
#define TILE  128
#define BK    64

typedef __bf16 bf16x8 __attribute__((ext_vector_type(8)));
typedef __bf16 bf16x4 __attribute__((ext_vector_type(4)));
typedef float  f32x4  __attribute__((ext_vector_type(4)));

// exp(LOG_NORM - 0.5*z^2), z=(c-1)/0.05  ==  exp2(LOG2K - 288.539008*(c-1)^2)
#define LOG2K      2.99618003f
#define NEG_COEF  -288.53900818f   // -0.5 * 400 / ln(2)

// Wave-per-row normalize for BOTH matrices; blocks 0..7 also zero d_out.
// 4 waves/block, 64 lanes x float4 = 256 floats = one row.
__global__ __launch_bounds__(256) void normalize2(
    const float* __restrict__ Ex, const float* __restrict__ Ey,
    __hip_bfloat16* __restrict__ Xn, __hip_bfloat16* __restrict__ Yn,
    float* __restrict__ out) {
    const int tid  = threadIdx.x;
    const int wave = tid >> 6;
    const int lane = tid & 63;
    const int gr   = blockIdx.x * 4 + wave;        // 0..16383

    if (blockIdx.x < 8) {                          // zero 8192 floats of out
        f32x4 z = {0.f, 0.f, 0.f, 0.f};
        ((f32x4*)out)[blockIdx.x * 256 + tid] = z;
    }

    const float* src; __hip_bfloat16* dst; int row;
    if (gr < NROWS) { src = Ex; dst = Xn; row = gr; }
    else            { src = Ey; dst = Yn; row = gr - NROWS; }

    const float4 v = *(const float4*)(src + (size_t)row * DDIM + lane * 4);
    float ss = v.x * v.x + v.y * v.y + v.z * v.z + v.w * v.w;
#pragma unroll
    for (int o = 32; o > 0; o >>= 1) ss += __shfl_xor(ss, o);
    const float inv = 1.0f / fmaxf(sqrtf(ss), 1e-8f);
    bf16x4 o4;
    o4[0] = (__bf16)(v.x * inv);
    o4[1] = (__bf16)(v.y * inv);
    o4[2] = (__bf16)(v.z * inv);
    o4[3] = (__bf16)(v.w * inv);
    *(bf16x4*)((__bf16*)dst + (size_t)row * DDIM + lane * 4) = o4;
}

__device__ inline void async_load16(const void* g, void* l) {
    __builtin_amdgcn_global_load_lds(
        (const __attribute__((address_space(1))) unsigned int*)g,
        (__attribute__((address_space(3))) unsigned int*)l, 16, 0, 0);
}

// C = Xn * Yn^T fused with gaussian + column-sum.
// 128x128 tile, 4 waves in 2x2, BK=64, mfma 16x16x32 bf16.
// LDS k-chunks XOR-swizzled by (row&7) to kill the 16-way bank conflict:
// LDS[row][kc] holds global k-chunk (kc ^ (row&7)).
__global__ __launch_bounds__(256) void cosgauss_gemm(
    const __hip_bfloat16* __restrict__ Xn,
    const __hip_bfloat16* __restrict__ Yn,
    float* __restrict__ out) {
    __shared__ __hip_bfloat16 As[TILE * BK];   // 16 KB
    __shared__ __hip_bfloat16 Bs[TILE * BK];   // 16 KB
    __shared__ float colpart[TILE];

    const int tid  = threadIdx.x;
    const int lane = tid & 63;
    const int w    = tid >> 6;       // wave 0..3
    const int wr   = w >> 1;         // wave row 0..1 (64 rows each)
    const int wc   = w & 1;          // wave col 0..1 (64 cols each)
    const int rowBase = blockIdx.y * TILE;
    const int colBase = blockIdx.x * TILE;

    const __hip_bfloat16* Ag = Xn + (size_t)rowBase * DDIM;
    const __hip_bfloat16* Bg = Yn + (size_t)colBase * DDIM;

    f32x4 acc[4][4] = {};

    const int lr = lane >> 3;                 // staging: row within 8-row chunk
    const int cbS = ((lane & 7) ^ lr) * 8;    // staging: SWIZZLED global k offset
    const int lm = lane & 15;                 // mfma: m (A) / n (B) index
    const int kq = lane >> 4;                 // mfma: k-quad
    const int sw = lm & 7;                    // read-side swizzle key (= row&7)

    for (int kt = 0; kt < DDIM; kt += BK) {
        __syncthreads();             // LDS reuse guard
#pragma unroll
        for (int j = 0; j < 4; ++j) {
            const int chunk = w * 4 + j;            // 0..15 (8 rows each)
            const int r = chunk * 8 + lr;
            async_load16(Ag + (size_t)r * DDIM + kt + cbS, (char*)As + chunk * 1024);
            async_load16(Bg + (size_t)r * DDIM + kt + cbS, (char*)Bs + chunk * 1024);
        }
        __syncthreads();             // waits vmcnt(0) for global_load_lds

        const __bf16* Ap = (const __bf16*)As;
        const __bf16* Bp = (const __bf16*)Bs;
#pragma unroll
        for (int kk = 0; kk < BK; kk += 32) {
            const int kco = ((kk >> 3) + kq) ^ sw;   // swizzled k-chunk index
            bf16x8 a[4], b[4];
#pragma unroll
            for (int rf = 0; rf < 4; ++rf)
                a[rf] = *(const bf16x8*)(Ap + (wr * 64 + rf * 16 + lm) * BK + kco * 8);
#pragma unroll
            for (int cf = 0; cf < 4; ++cf)
                b[cf] = *(const bf16x8*)(Bp + (wc * 64 + cf * 16 + lm) * BK + kco * 8);
#pragma unroll
            for (int rf = 0; rf < 4; ++rf)
#pragma unroll
                for (int cf = 0; cf < 4; ++cf)
                    acc[rf][cf] = __builtin_amdgcn_mfma_f32_16x16x32_bf16(
                        a[rf], b[cf], acc[rf][cf], 0, 0, 0);
        }
    }

    // Epilogue: gaussian + column sums.
    // C/D layout: col = lane&15, row = (lane>>4)*4 + reg  [m89/m91 verified]
    float s[4];
#pragma unroll
    for (int cf = 0; cf < 4; ++cf) {
        float t = 0.0f;
#pragma unroll
        for (int rf = 0; rf < 4; ++rf) {
#pragma unroll
            for (int i = 0; i < 4; ++i) {
                const float d = acc[rf][cf][i] - 1.0f;
                t += exp2f(fmaf(d * d, NEG_COEF, LOG2K));
            }
        }
        t += __shfl_xor(t, 16);
        t += __shfl_xor(t, 32);
        s[cf] = t;
    }
    const float v = (lane < 16) ? s[0] : (lane < 32) ? s[1] : (lane < 48) ? s[2] : s[3];
    const int c = wc * 64 + lane;    // 0..127 within tile
    if (wr == 0) colpart[c] = v;
    __syncthreads();
    if (wr == 1) atomicAdd(&out[colBase + c], v + colpart[c]);
}

extern "C" void kernel_launch(void* const* d_in, const int* in_sizes, int n_in,
                              void* d_out, int out_size, void* d_ws, size_t ws_size,
                              hipStream_t stream) {
    const float* Ex = (const float*)d_in[0];
    const float* Ey = (const float*)d_in[1];
    float* out = (float*)d_out;

    __hip_bfloat16* Xn = (__hip_bfloat16*)d_ws;                    // 4 MB
    __hip_bfloat16* Yn = Xn + (size_t)NROWS * DDIM;                // +4 MB

    normalize2<<<(2 * NROWS) / 4, 256, 0, stream>>>(Ex, Ey, Xn, Yn, out);

    dim3 grid(NROWS / TILE, NROWS / TILE);                         // 64 x 64 tiles
    cosgauss_gemm<<<grid, 256, 0, stream>>>(Xn, Yn, out);
}